// Round 7
// baseline (1124.802 us; speedup 1.0000x reference)
//
#include <hip/hip_runtime.h>
#include <stdint.h>
#include <math.h>

#define NB 4
#define NU 1024
#define NS 256
#define NF 16
#define ND 256
#define NEGV -1000000000.0f
#define NBLK (NB * NS)   // 1024 blocks in persistent-grid kernel
#define VBIT (1 << 14)
#define AGENT __HIP_MEMORY_SCOPE_AGENT
#define SPINCAP (1 << 20)

// ctrl layout (unsigned words):
//   [32*b]            rel[b]     release word, batch b (128B padded)
//   [256], [257]      det[2]     connect dtype detection
//   [1024 + bs*32]    arrive[bs] per-block arrival slot (128B padded)

// ---------- detect connect dtype (int32 / float32 / byte), parallel ----------
__global__ __launch_bounds__(256) void k_detect(const uint8_t* __restrict__ conn,
                                                unsigned* __restrict__ det) {
  int i = blockIdx.x * 256 + threadIdx.x;   // 64 blocks -> 16384 threads x 4B = 64KB sample
  uchar4 v = ((const uchar4*)conn)[i];
  bool c0 = v.x != 0;
  bool c123 = (v.y | v.z | v.w) != 0;
  unsigned long long m0 = __ballot(c0);
  unsigned long long m1 = __ballot(c123);
  if ((threadIdx.x & 63) == 0) {
    if (m0) atomicOr(&det[0], 1u);
    if (m1) atomicOr(&det[1], 1u);
  }
}

// ---------- transpose connect -> bitmask [b][s][u/32], coalesced via LDS ----------
__global__ __launch_bounds__(256) void k_transpose(const uint8_t* __restrict__ conn,
                                                   const unsigned* __restrict__ det,
                                                   uint32_t* __restrict__ connT) {
  unsigned d0 = det[0], d1 = det[1];
  int f = (d1 == 0) ? 0 : ((d0 == 0) ? 1 : 2);
  int blk = blockIdx.x;          // b*32 + ug ; 128 blocks
  int b = blk >> 5, ug = blk & 31;
  int u0 = ug * 32;
  int t = threadIdx.x;
  __shared__ uint8_t sm[32][260];
#pragma unroll 4
  for (int r = 0; r < 32; ++r) {
    int e = (b * NU + u0 + r) * NS + t;
    bool nz;
    if (f == 0)      nz = ((const int*)conn)[e] != 0;
    else if (f == 1) nz = ((const float*)conn)[e] != 0.0f;
    else             nz = conn[e] != 0;
    sm[r][t] = nz ? 1 : 0;
  }
  __syncthreads();
  uint32_t word = 0;
#pragma unroll
  for (int j = 0; j < 32; ++j) word |= (uint32_t)sm[j][t] << j;
  connT[(b * NS + t) * 32 + ug] = word;
}

// ---------- WS_K[d][c] = sum_e W_k[d][e] * W_state[e][c] (e ascending order) ----------
__global__ __launch_bounds__(256) void k_weights(const float* __restrict__ W_state,
                                                 const float* __restrict__ W_k,
                                                 float* __restrict__ WS_K) {
  int d = threadIdx.x;
  const float4* wk4 = (const float4*)(W_k + d * ND);
  const float4* ws4 = (const float4*)W_state;
  float a0 = 0, a1 = 0, a2 = 0, a3 = 0;
  for (int e4 = 0; e4 < ND / 4; ++e4) {
    float4 k4 = wk4[e4];
    float4 w0 = ws4[e4 * 4 + 0];
    a0 += k4.x * w0.x; a1 += k4.x * w0.y; a2 += k4.x * w0.z; a3 += k4.x * w0.w;
    float4 w1 = ws4[e4 * 4 + 1];
    a0 += k4.y * w1.x; a1 += k4.y * w1.y; a2 += k4.y * w1.z; a3 += k4.y * w1.w;
    float4 w2 = ws4[e4 * 4 + 2];
    a0 += k4.z * w2.x; a1 += k4.z * w2.y; a2 += k4.z * w2.z; a3 += k4.z * w2.w;
    float4 w3 = ws4[e4 * 4 + 3];
    a0 += k4.w * w3.x; a1 += k4.w * w3.y; a2 += k4.w * w3.z; a3 += k4.w * w3.w;
  }
  ((float4*)WS_K)[d] = make_float4(a0, a1, a2, a3);
}

// ---------- f32 GEMM, double-buffered LDS (accumulation order bit-identical) ----------
__global__ __launch_bounds__(256) void k_gemm(
    const float* __restrict__ A, const float* __restrict__ Bm, float* __restrict__ C,
    int K, int lda, int ldb, int ldc, long sA, long sB, long sC,
    const float* __restrict__ biasA, float alpha) {
  int z = blockIdx.z;
  A += (size_t)z * sA; Bm += (size_t)z * sB; C += (size_t)z * sC;
  int m0 = blockIdx.y * 64, n0 = blockIdx.x * 64;
  int t = threadIdx.x;
  int tx = t & 15, ty = t >> 4;
  __shared__ float As[2][16][68];
  __shared__ float Bs[2][16][68];
  float acc[4][4];
#pragma unroll
  for (int i = 0; i < 4; i++)
#pragma unroll
    for (int j = 0; j < 4; j++) acc[i][j] = 0.f;
  int lr = t >> 2;
  int kq = (t & 3) * 4;

  {
    float4 av = *(const float4*)(A + (size_t)(m0 + lr) * lda + kq);
    if (biasA) {
      const float* bp = biasA + kq;
      av.x += bp[0]; av.y += bp[1]; av.z += bp[2]; av.w += bp[3];
    }
    As[0][kq + 0][lr] = av.x; As[0][kq + 1][lr] = av.y;
    As[0][kq + 2][lr] = av.z; As[0][kq + 3][lr] = av.w;
    float4 bv = *(const float4*)(Bm + (size_t)(n0 + lr) * ldb + kq);
    Bs[0][kq + 0][lr] = bv.x; Bs[0][kq + 1][lr] = bv.y;
    Bs[0][kq + 2][lr] = bv.z; Bs[0][kq + 3][lr] = bv.w;
  }
  __syncthreads();

  int nt = K >> 4;
  for (int ti = 0; ti < nt; ++ti) {
    int buf = ti & 1;
    float4 av2, bv2;
    bool more = (ti + 1 < nt);
    if (more) {
      int k0 = (ti + 1) << 4;
      av2 = *(const float4*)(A + (size_t)(m0 + lr) * lda + k0 + kq);
      if (biasA) {
        const float* bp = biasA + k0 + kq;
        av2.x += bp[0]; av2.y += bp[1]; av2.z += bp[2]; av2.w += bp[3];
      }
      bv2 = *(const float4*)(Bm + (size_t)(n0 + lr) * ldb + k0 + kq);
    }
#pragma unroll
    for (int k = 0; k < 16; ++k) {
      float4 a = *(const float4*)&As[buf][k][ty * 4];
      float4 bb = *(const float4*)&Bs[buf][k][tx * 4];
      float am[4] = {a.x, a.y, a.z, a.w};
      float bn[4] = {bb.x, bb.y, bb.z, bb.w};
#pragma unroll
      for (int i = 0; i < 4; ++i)
#pragma unroll
        for (int j = 0; j < 4; ++j) acc[i][j] += am[i] * bn[j];
    }
    if (more) {
      __syncthreads();
      int nb = buf ^ 1;
      As[nb][kq + 0][lr] = av2.x; As[nb][kq + 1][lr] = av2.y;
      As[nb][kq + 2][lr] = av2.z; As[nb][kq + 3][lr] = av2.w;
      Bs[nb][kq + 0][lr] = bv2.x; Bs[nb][kq + 1][lr] = bv2.y;
      Bs[nb][kq + 2][lr] = bv2.z; Bs[nb][kq + 3][lr] = bv2.w;
      __syncthreads();
    }
  }
#pragma unroll
  for (int i = 0; i < 4; ++i) {
    float4 o = make_float4(acc[i][0] * alpha, acc[i][1] * alpha,
                           acc[i][2] * alpha, acc[i][3] * alpha);
    *(float4*)(C + (size_t)(m0 + ty * 4 + i) * ldc + n0 + tx * 4) = o;
  }
}

// ---------- qc[bu][c] = inv_sqrt_d * sum_d q[bu][d] * WS_K[d][c], wave per row ----------
__global__ __launch_bounds__(256) void k_qc(const float* __restrict__ q,
                                            const float* __restrict__ WS_K,
                                            float* __restrict__ qc) {
  int row = blockIdx.x * 4 + (threadIdx.x >> 6);
  int ln = threadIdx.x & 63;
  const float* qr = q + (size_t)row * ND;
  float a0 = 0, a1 = 0, a2 = 0, a3 = 0;
  for (int d = ln; d < ND; d += 64) {
    float qv = qr[d];
    float4 w = ((const float4*)WS_K)[d];
    a0 += qv * w.x; a1 += qv * w.y; a2 += qv * w.z; a3 += qv * w.w;
  }
  for (int o = 32; o; o >>= 1) {
    a0 += __shfl_xor(a0, o); a1 += __shfl_xor(a1, o);
    a2 += __shfl_xor(a2, o); a3 += __shfl_xor(a3, o);
  }
  if (ln == 0)
    ((float4*)qc)[row] = make_float4(a0 * 0.0625f, a1 * 0.0625f, a2 * 0.0625f, a3 * 0.0625f);
}

// ---------- per-batch barrier: sc0sc1 store-slots + scanner block, no fences ----------
__device__ __forceinline__ void bsync2(unsigned* arrive, unsigned* rel,
                                       int b, int sown, unsigned e) {
  __shared__ int nr;
  __syncthreads();
  if (sown == 0) {
    if (threadIdx.x == 0) asm volatile("s_waitcnt vmcnt(0)" ::: "memory");
    unsigned* slot = arrive + (unsigned)(b * NS + threadIdx.x) * 32u;
    bool ready = (threadIdx.x == 0);
    int iters = 0;
    for (;;) {
      if (threadIdx.x == 0) nr = 0;
      __syncthreads();
      if (!ready && __hip_atomic_load(slot, __ATOMIC_RELAXED, AGENT) >= e) ready = true;
      unsigned long long mm = __ballot(!ready);
      if (mm && (threadIdx.x & 63) == 0) atomicOr(&nr, 1);
      __syncthreads();
      if (nr == 0 || ++iters > SPINCAP) break;
      __builtin_amdgcn_s_sleep(1);
    }
    if (threadIdx.x == 0)
      __hip_atomic_store(rel, e, __ATOMIC_RELAXED, AGENT);
  } else if (threadIdx.x == 0) {
    asm volatile("s_waitcnt vmcnt(0)" ::: "memory");   // proposals drained to coherent point
    __hip_atomic_store(arrive + (unsigned)(b * NS + sown) * 32u, e,
                       __ATOMIC_RELAXED, AGENT);
    int iters = 0;
    while (__hip_atomic_load(rel, __ATOMIC_RELAXED, AGENT) < e) {
      __builtin_amdgcn_s_sleep(2);
      if (++iters > SPINCAP) break;
    }
  }
  __syncthreads();
}

// ---------- the 32-step allocator: one block per (b,s), all state local ----------
__global__ __launch_bounds__(256, 4) void k_steps(
    const float* __restrict__ L0T, const float* __restrict__ qc,
    const float* __restrict__ users, const float* __restrict__ servers,
    const uint32_t* __restrict__ connT, const float* __restrict__ fd_onehot,
    const float* __restrict__ W_us, const float* __restrict__ fd_alpha,
    const float* __restrict__ fd_beta, const float* __restrict__ score_bias,
    unsigned* __restrict__ pinfoG, unsigned* __restrict__ plogG,
    unsigned* __restrict__ plsbG,
    unsigned* __restrict__ ctrl,
    uint32_t* __restrict__ allocW, float* __restrict__ capF, float* __restrict__ out) {
  __shared__ unsigned long long keyS[NU];
  __shared__ float lsumS[NU];
  __shared__ uint32_t fdS[NU];
  __shared__ float wred[8];
  __shared__ int wredi[4];
  __shared__ float bcv;
  __shared__ int bca;
  __shared__ int sAny;
  __shared__ float capS[4];

  const int bs = blockIdx.x;
  const int b = bs >> 8;
  const int sown = bs & 255;
  const int tid = threadIdx.x;
  const int wv = tid >> 6, ln = tid & 63;

  unsigned* rel = ctrl + 32 * b;
  unsigned* arrive = ctrl + 1024;

  const float a_ = fd_alpha[0], be_ = fd_beta[0];
  const float t0 = tanhf(be_), t1 = tanhf(a_ + be_);
  const float sb = score_bias[0];
  const float w0 = W_us[0], w1 = W_us[1], w2 = W_us[2];

  int fid = 0;
  for (int f = 0; f < NF; ++f)
    if (fd_onehot[bs * NF + f] > 0.5f) { fid = f; break; }

  const float ic0 = servers[bs * 8 + 3], ic1 = servers[bs * 8 + 4];
  const float ic2 = servers[bs * 8 + 5], ic3 = servers[bs * 8 + 6];
  const float m0d = fmaxf(ic0, 1e-6f), m1d = fmaxf(ic1, 1e-6f);
  const float m2d = fmaxf(ic2, 1e-6f), m3d = fmaxf(ic3, 1e-6f);
  if (tid == 0) { capS[0] = ic0; capS[1] = ic1; capS[2] = ic2; capS[3] = ic3; }

  float L0c[4], qc0[4], qc1[4], qc2[4], qc3[4], nax[4], nay[4], nbx[4], nby[4];
  uint32_t connw[4];
  uint32_t upk[4] = {0, 0, 0, 0};
  float usv[4];
  float logpv[4] = {0, 0, 0, 0};
  uint32_t abits = 0;
#pragma unroll
  for (int it = 0; it < 4; ++it) {
    int u = it * 256 + tid, gu = b * NU + u;
    L0c[it] = L0T[(size_t)bs * NU + u];
    float4 q4 = *(const float4*)(qc + gu * 4);
    qc0[it] = q4.x; qc1[it] = q4.y; qc2[it] = q4.z; qc3[it] = q4.w;
    float2 nA = *(const float2*)(users + gu * 8 + 2);
    float2 nB2 = *(const float2*)(users + gu * 8 + 4);
    nax[it] = nA.x; nay[it] = nA.y; nbx[it] = nB2.x; nby[it] = nB2.y;
    connw[it] = connT[bs * 32 + it * 8 + (tid >> 5)];
    usv[it] = w1;
  }
  for (int i = tid; i < NU; i += 256) { keyS[i] = 0ull; lsumS[i] = 0.f; fdS[i] = 0u; }
  __syncthreads();

  for (int step = 0; step < 32; ++step) {
    float c0 = capS[0], c1 = capS[1], c2 = capS[2], c3 = capS[3];
    float cr0 = c0 / m0d, cr1 = c1 / m1d, cr2 = c2 / m2d, cr3 = c3 / m3d;
    float cand[4];
    float lmax = NEGV;
    int larg = 0x7fffffff;
#pragma unroll
    for (int it = 0; it < 4; ++it) {
      int u = it * 256 + tid;
      bool el = ((connw[it] >> (tid & 31)) & 1u) && !((abits >> it) & 1u) &&
                ((upk[it] & 0x30000u) != 0x30000u) &&
                c0 >= nax[it] && c1 >= nay[it] && c2 >= nbx[it] && c3 >= nby[it];
      float tt = ((upk[it] >> fid) & 1u) ? t0 : t1;
      float lg = L0c[it] + qc0[it] * cr0 + qc1[it] * cr1 + qc2[it] * cr2 + qc3[it] * cr3 +
                 sb + tt + usv[it];
      float cv = el ? lg : NEGV;
      cand[it] = cv;
      if (cv > lmax || (cv == lmax && u < larg)) { lmax = cv; larg = u; }
    }
    for (int o = 32; o; o >>= 1) {
      float ov = __shfl_xor(lmax, o);
      int oa = __shfl_xor(larg, o);
      if (ov > lmax || (ov == lmax && oa < larg)) { lmax = ov; larg = oa; }
    }
    if (ln == 0) { wred[wv] = lmax; wredi[wv] = larg; }
    __syncthreads();
    if (tid == 0) {
      float m = wred[0]; int a = wredi[0];
      for (int i = 1; i < 4; ++i)
        if (wred[i] > m || (wred[i] == m && wredi[i] < a)) { m = wred[i]; a = wredi[i]; }
      bcv = m; bca = a;
    }
    __syncthreads();
    float maxv = bcv;
    int argu = bca;
    float ls = expf(cand[0] - maxv) + expf(cand[1] - maxv) +
               expf(cand[2] - maxv) + expf(cand[3] - maxv);
    for (int o = 32; o; o >>= 1) ls += __shfl_xor(ls, o);
    if (ln == 0) wred[4 + wv] = ls;
    __syncthreads();
    if (tid == 0) {
      float s4 = wred[4] + wred[5] + wred[6] + wred[7];
      int validb = (maxv > -1e8f) ? VBIT : 0;
      int par = (step & 1) * NBLK;
      __hip_atomic_store(&pinfoG[par + bs], (unsigned)(argu | (fid << 10) | validb),
                         __ATOMIC_RELAXED, AGENT);
      __hip_atomic_store(&plogG[par + bs], __float_as_uint(maxv),
                         __ATOMIC_RELAXED, AGENT);
      __hip_atomic_store(&plsbG[par + bs], __float_as_uint(-logf(s4)),
                         __ATOMIC_RELAXED, AGENT);
    }

    bsync2(arrive, rel, b, sown, (unsigned)(step + 1));

    {
      int pbase = (step & 1) * NBLK + b * NS;
      unsigned pi = __hip_atomic_load(&pinfoG[pbase + tid], __ATOMIC_RELAXED, AGENT);
      if (tid == 0) sAny = 0;
      __syncthreads();
      unsigned long long mm = __ballot((pi & VBIT) != 0);
      if (mm && (tid & 63) == 0) atomicOr(&sAny, 1);
      __syncthreads();
      if (sAny == 0) break;
      if (pi & VBIT) {
        int pu = pi & 1023;
        unsigned vb = __hip_atomic_load(&plogG[pbase + tid], __ATOMIC_RELAXED, AGENT);
        float lsb = __uint_as_float(
            __hip_atomic_load(&plsbG[pbase + tid], __ATOMIC_RELAXED, AGENT));
        unsigned enc = (vb & 0x80000000u) ? ~vb : (vb | 0x80000000u);
        unsigned long long key = ((unsigned long long)enc << 32) | (unsigned)(255 - tid);
        atomicMax(&keyS[pu], key);
        atomicAdd(&lsumS[pu], lsb);
        atomicOr(&fdS[pu], 1u << ((pi >> 10) & 15));
      }
      __syncthreads();
#pragma unroll
      for (int it = 0; it < 4; ++it) {
        unsigned long long key = keyS[it * 256 + tid];
        if (key) {
          int u = it * 256 + tid;
          float lsum = lsumS[u];
          uint32_t fda = fdS[u];
          keyS[u] = 0ull; lsumS[u] = 0.f; fdS[u] = 0u;
          int bests = 255 - (int)(key & 0xFFFFFFFFull);
          logpv[it] += lsum;
          uint32_t pk = upk[it];
          int r = (int)((pk >> 16) & 3) + 1;
          upk[it] = ((pk | fda) & 0xFFFFu) | ((uint32_t)r << 16);
          float rf = (float)r;
          usv[it] = w0 * (rf / 3.0f) + w1 * (fmaxf(3.0f - rf, 0.f) / 3.0f) +
                    ((r == 2) ? w2 : 0.f);
          if (bests == sown) {
            abits |= 1u << it;
            capS[0] = fmaxf(c0 - nax[it], 0.f);
            capS[1] = fmaxf(c1 - nay[it], 0.f);
            capS[2] = fmaxf(c2 - nbx[it], 0.f);
            capS[3] = fmaxf(c3 - nby[it], 0.f);
          }
        }
      }
      __syncthreads();
    }
  }

#pragma unroll
  for (int it = 0; it < 4; ++it) {
    unsigned long long m = __ballot((abits >> it) & 1u);
    if (ln == 0)
      *(unsigned long long*)&allocW[bs * 32 + it * 8 + wv * 2] = m;
  }
  if (tid == 0)
    *(float4*)(capF + bs * 4) = make_float4(capS[0], capS[1], capS[2], capS[3]);
  if (sown == 0) {
    float a = logpv[0] + logpv[1] + logpv[2] + logpv[3];
    for (int o = 32; o; o >>= 1) a += __shfl_xor(a, o);
    if (ln == 0) wred[wv] = a;
    __syncthreads();
    if (tid == 0) out[b] = wred[0] + wred[1] + wred[2] + wred[3];
  }
}

// ================= fallback path (round-1, proven) =================
__global__ __launch_bounds__(256) void k_init(
    const float* __restrict__ servers, const float* __restrict__ fd_onehot,
    const float* __restrict__ W_us, const float* __restrict__ fd_alpha,
    const float* __restrict__ fd_beta, const float* __restrict__ score_bias,
    float* __restrict__ consts, int* __restrict__ rc, float* __restrict__ logp,
    uint32_t* __restrict__ fdmask, float* __restrict__ us_add,
    float* __restrict__ cap, int* __restrict__ fd_id, uint32_t* __restrict__ allocT) {
  int i = blockIdx.x * 256 + threadIdx.x;
  if (i == 0) {
    float a = fd_alpha[0], be = fd_beta[0];
    consts[0] = tanhf(be);
    consts[1] = tanhf(a + be);
    consts[2] = score_bias[0];
    consts[3] = W_us[0]; consts[4] = W_us[1]; consts[5] = W_us[2];
  }
  if (i < NB * NU) {
    rc[i] = 0; logp[i] = 0.f; fdmask[i] = 0u;
    us_add[i] = W_us[1];
  }
  if (i < NB * NS) {
    int fid = 0;
    for (int f = 0; f < NF; ++f) if (fd_onehot[i * NF + f] > 0.5f) { fid = f; break; }
    fd_id[i] = fid;
    for (int c = 0; c < 4; ++c) cap[i * 4 + c] = servers[i * 8 + 3 + c];
  }
  allocT[i] = 0u;
}

__global__ __launch_bounds__(256) void k_stepA(
    const float* __restrict__ L0T, const float* __restrict__ qc,
    const float* __restrict__ us_add, const int* __restrict__ rc,
    const uint32_t* __restrict__ connT, const uint32_t* __restrict__ allocT,
    const uint32_t* __restrict__ fdmask, const int* __restrict__ fd_id,
    const float* __restrict__ cap, const float* __restrict__ servers,
    const float* __restrict__ users, const float* __restrict__ consts,
    int* __restrict__ prop_u, float* __restrict__ prop_logit,
    float* __restrict__ logp_bs, int* __restrict__ valid) {
  int bs = blockIdx.x;
  int b = bs >> 8;
  int tid = threadIdx.x;
  float t0 = consts[0], t1 = consts[1], sb = consts[2];
  float4 c4 = *(const float4*)(cap + bs * 4);
  const float* srow = servers + bs * 8;
  float cr0 = c4.x / fmaxf(srow[3], 1e-6f);
  float cr1 = c4.y / fmaxf(srow[4], 1e-6f);
  float cr2 = c4.z / fmaxf(srow[5], 1e-6f);
  float cr3 = c4.w / fmaxf(srow[6], 1e-6f);
  int fid = fd_id[bs];
  const float* L0row = L0T + (size_t)bs * NU;
  int ubase = b * NU;
  float cand[4];
  float lmax = NEGV;
  int larg = tid;
#pragma unroll
  for (int it = 0; it < 4; ++it) {
    int u = (it << 8) + tid;
    int gu = ubase + u;
    uint32_t cw = connT[bs * 32 + (u >> 5)];
    uint32_t aw = allocT[bs * 32 + (u >> 5)];
    uint32_t bp = (uint32_t)(u & 31);
    bool el = ((cw >> bp) & 1u) && !((aw >> bp) & 1u) && (rc[gu] < 3);
    const float* up = users + gu * 8;
    float2 nA = *(const float2*)(up + 2);
    float2 nB = *(const float2*)(up + 4);
    el = el && (c4.x >= nA.x) && (c4.y >= nA.y) && (c4.z >= nB.x) && (c4.w >= nB.y);
    float4 q4 = *(const float4*)(qc + gu * 4);
    float tt = ((fdmask[gu] >> fid) & 1u) ? t0 : t1;
    float lg = L0row[u] + q4.x * cr0 + q4.y * cr1 + q4.z * cr2 + q4.w * cr3
               + sb + tt + us_add[gu];
    float cv = el ? lg : NEGV;
    cand[it] = cv;
    if (cv > lmax) { lmax = cv; larg = u; }
  }
  __shared__ float smax[256];
  __shared__ int sarg[256];
  smax[tid] = lmax; sarg[tid] = larg;
  __syncthreads();
  for (int o2 = 128; o2 > 0; o2 >>= 1) {
    if (tid < o2) {
      float v2 = smax[tid + o2]; int a2 = sarg[tid + o2];
      if (v2 > smax[tid] || (v2 == smax[tid] && a2 < sarg[tid])) {
        smax[tid] = v2; sarg[tid] = a2;
      }
    }
    __syncthreads();
  }
  float maxv = smax[0];
  int argu = sarg[0];
  __syncthreads();
  float ls = 0.f;
#pragma unroll
  for (int it = 0; it < 4; ++it) ls += expf(cand[it] - maxv);
  smax[tid] = ls;
  __syncthreads();
  for (int o2 = 128; o2 > 0; o2 >>= 1) {
    if (tid < o2) smax[tid] += smax[tid + o2];
    __syncthreads();
  }
  if (tid == 0) {
    prop_u[bs] = argu;
    prop_logit[bs] = maxv;
    valid[bs] = (maxv > -1e8f) ? 1 : 0;
    logp_bs[bs] = -logf(smax[0]);
  }
}

__global__ __launch_bounds__(256) void k_stepB(
    const int* __restrict__ prop_u, const float* __restrict__ prop_logit,
    const float* __restrict__ logp_bs, const int* __restrict__ valid,
    const int* __restrict__ fd_id, const float* __restrict__ users,
    const float* __restrict__ consts,
    uint32_t* __restrict__ allocT, int* __restrict__ rc, float* __restrict__ cap,
    float* __restrict__ logp, uint32_t* __restrict__ fdmask, float* __restrict__ us_add) {
  int id = blockIdx.x * 256 + threadIdx.x;
  int b = id >> 10;
  int u = id & 1023;
  int tid = threadIdx.x;
  __shared__ int spu[256];
  __shared__ float spl[256];
  __shared__ float slb[256];
  __shared__ int sv[256];
  __shared__ int sfid[256];
  int si = b * NS + tid;
  spu[tid] = prop_u[si]; spl[tid] = prop_logit[si]; slb[tid] = logp_bs[si];
  sv[tid] = valid[si]; sfid[tid] = fd_id[si];
  __syncthreads();
  float bestv = NEGV;
  int bests = -1;
  float lsum = 0.f;
  uint32_t fdadd = 0;
  for (int s = 0; s < NS; ++s) {
    if (sv[s] && spu[s] == u) {
      lsum += slb[s];
      fdadd |= 1u << sfid[s];
      float v = spl[s];
      if (v > bestv) { bestv = v; bests = s; }
    }
  }
  logp[id] += lsum;
  if (fdadd) fdmask[id] |= fdadd;
  int r = rc[id];
  if (bests >= 0) {
    atomicOr(&allocT[(b * NS + bests) * 32 + (u >> 5)], 1u << (u & 31));
    r += 1;
    rc[id] = r;
    const float* up = users + id * 8;
    float2 nA = *(const float2*)(up + 2);
    float2 nB = *(const float2*)(up + 4);
    float* cp = cap + (b * NS + bests) * 4;
    cp[0] = fmaxf(cp[0] - nA.x, 0.f);
    cp[1] = fmaxf(cp[1] - nA.y, 0.f);
    cp[2] = fmaxf(cp[2] - nB.x, 0.f);
    cp[3] = fmaxf(cp[3] - nB.y, 0.f);
  }
  float rf = (float)r;
  float wus0 = consts[3], wus1 = consts[4], wus2 = consts[5];
  us_add[id] = wus0 * (rf / 3.0f) + wus1 * (fmaxf(3.0f - rf, 0.f) / 3.0f)
               + ((r == 2) ? wus2 : 0.f);
}

__global__ __launch_bounds__(256) void k_logpsum(const float* __restrict__ logp,
                                                 float* __restrict__ out) {
  int b = blockIdx.x;
  int tid = threadIdx.x;
  __shared__ float sred[256];
  float acc = 0.f;
  for (int it = 0; it < 4; ++it) acc += logp[b * NU + it * 256 + tid];
  sred[tid] = acc;
  __syncthreads();
  for (int o2 = 128; o2 > 0; o2 >>= 1) {
    if (tid < o2) sred[tid] += sred[tid + o2];
    __syncthreads();
  }
  if (tid == 0) out[b] = sred[0];
}

// ---------- expand bitmask + cap to output layout ----------
__global__ __launch_bounds__(256) void k_store(const uint32_t* __restrict__ allocW,
                                               const float* __restrict__ capF,
                                               float* __restrict__ out) {
  int blk = blockIdx.x;
  if (blk < 1024) {
    int i4 = (blk * 256 + threadIdx.x) * 4;
    int b = i4 >> 18;
    int u = (i4 >> 8) & 1023;
    int s = i4 & 255;
    int base = (b * NS + s) * 32 + (u >> 5);
    uint32_t bitm = 1u << (u & 31);
    float4 o;
    o.x = (allocW[base] & bitm) ? 1.f : 0.f;
    o.y = (allocW[base + 32] & bitm) ? 1.f : 0.f;
    o.z = (allocW[base + 64] & bitm) ? 1.f : 0.f;
    o.w = (allocW[base + 96] & bitm) ? 1.f : 0.f;
    *(float4*)(out + 4 + i4) = o;
  } else {
    int b = blk - 1024;
    int s = threadIdx.x;
    float4 c = *(const float4*)(capF + (b * NS + s) * 4);
    *(float4*)(out + 4 + NB * NU * NS + (b * NS + s) * 4) = c;
  }
}

extern "C" void kernel_launch(void* const* d_in, const int* in_sizes, int n_in,
                              void* d_out, int out_size, void* d_ws, size_t ws_size,
                              hipStream_t stream) {
  const float* user_enc = (const float*)d_in[0];
  const float* server_enc = (const float*)d_in[1];
  const float* users = (const float*)d_in[2];
  const float* servers = (const float*)d_in[3];
  const uint8_t* connect = (const uint8_t*)d_in[4];
  const float* fd_onehot = (const float*)d_in[5];
  const float* W_state = (const float*)d_in[6];
  const float* b_state = (const float*)d_in[7];
  const float* W_q = (const float*)d_in[8];
  const float* W_k = (const float*)d_in[9];
  const float* W_us = (const float*)d_in[10];
  const float* fd_alpha = (const float*)d_in[11];
  const float* fd_beta = (const float*)d_in[12];
  const float* score_bias = (const float*)d_in[13];

  char* ws = (char*)d_ws;
  size_t off = 0;
  auto take = [&](size_t bytes) -> void* {
    size_t cur = off;
    off = (off + bytes + 255) & ~(size_t)255;
    return (void*)(ws + cur);
  };
  const size_t ctrlBytes = (size_t)(1024 + NBLK * 32) * 4;   // 135168
  unsigned* ctrl = (unsigned*)take(ctrlBytes);
  unsigned* det = ctrl + 256;
  float* q = (float*)take((size_t)NB * NU * ND * 4);
  float* kb = (float*)take((size_t)NB * NS * ND * 4);
  float* L0T = (float*)take((size_t)NB * NS * NU * 4);
  float* qc = (float*)take((size_t)NB * NU * 4 * 4);
  float* WS_K = (float*)take((size_t)ND * 4 * 4);
  uint32_t* connT = (uint32_t*)take((size_t)NB * NS * 32 * 4);
  unsigned* pinfoG = (unsigned*)take((size_t)2 * NBLK * 4);
  unsigned* plogG = (unsigned*)take((size_t)2 * NBLK * 4);
  unsigned* plsbG = (unsigned*)take((size_t)2 * NBLK * 4);
  uint32_t* allocW = (uint32_t*)take((size_t)NB * NS * 32 * 4);
  float* capF = (float*)take((size_t)NB * NS * 4 * 4);
  // fallback-only state
  float* consts = (float*)take(256);
  uint32_t* fdmask = (uint32_t*)take((size_t)NB * NU * 4);
  int* fd_id = (int*)take((size_t)NB * NS * 4);
  int* rc = (int*)take((size_t)NB * NU * 4);
  float* us_add = (float*)take((size_t)NB * NU * 4);
  float* logp = (float*)take((size_t)NB * NU * 4);
  int* prop_u = (int*)take((size_t)NB * NS * 4);
  float* prop_logit = (float*)take((size_t)NB * NS * 4);
  float* logp_bs = (float*)take((size_t)NB * NS * 4);
  int* valid = (int*)take((size_t)NB * NS * 4);
  float* outp = (float*)d_out;

  hipMemsetAsync(ctrl, 0, ctrlBytes, stream);
  k_detect<<<64, 256, 0, stream>>>(connect, det);
  k_transpose<<<128, 256, 0, stream>>>(connect, det, connT);
  k_weights<<<1, 256, 0, stream>>>(W_state, W_k, WS_K);
  k_gemm<<<dim3(ND / 64, (NB * NU) / 64, 1), 256, 0, stream>>>(
      user_enc, W_q, q, ND, ND, ND, ND, 0, 0, 0, nullptr, 1.f);
  k_gemm<<<dim3(ND / 64, (NB * NS) / 64, 1), 256, 0, stream>>>(
      server_enc, W_k, kb, ND, ND, ND, ND, 0, 0, 0, b_state, 1.f);
  k_qc<<<NB * NU / 4, 256, 0, stream>>>(q, WS_K, qc);
  k_gemm<<<dim3(NU / 64, NS / 64, NB), 256, 0, stream>>>(
      kb, q, L0T, ND, ND, ND, NU,
      (long)NS * ND, (long)NU * ND, (long)NS * NU, nullptr, 0.0625f);

  // ---- residency check (host-only queries: safe under graph capture) ----
  int dev = 0;
  hipGetDevice(&dev);
  int nCU = 0, occ = 0;
  hipDeviceGetAttribute(&nCU, hipDeviceAttributeMultiprocessorCount, dev);
  hipError_t oe = hipOccupancyMaxActiveBlocksPerMultiprocessor(&occ, (const void*)k_steps, 256, 0);
  bool usePersist = (oe == hipSuccess) && ((long)occ * nCU >= NBLK);

  if (usePersist) {
    // plain launch: grid == co-residency capacity; hand-rolled per-batch barrier inside
    k_steps<<<dim3(NBLK), dim3(256), 0, stream>>>(
        L0T, qc, users, servers, connT, fd_onehot, W_us, fd_alpha, fd_beta, score_bias,
        pinfoG, plogG, plsbG, ctrl, allocW, capF, outp);
  } else {
    k_init<<<128, 256, 0, stream>>>(servers, fd_onehot, W_us, fd_alpha, fd_beta, score_bias,
                                    consts, rc, logp, fdmask, us_add, capF, fd_id, allocW);
    for (int step = 0; step < 32; ++step) {
      k_stepA<<<NB * NS, 256, 0, stream>>>(L0T, qc, us_add, rc, connT, allocW, fdmask, fd_id,
                                           capF, servers, users, consts,
                                           prop_u, prop_logit, logp_bs, valid);
      k_stepB<<<(NB * NU) / 256, 256, 0, stream>>>(prop_u, prop_logit, logp_bs, valid, fd_id,
                                                   users, consts,
                                                   allocW, rc, capF, logp, fdmask, us_add);
    }
    k_logpsum<<<NB, 256, 0, stream>>>(logp, (float*)d_out);
  }
  k_store<<<1028, 256, 0, stream>>>(allocW, capF, (float*)d_out);
}

// Round 8
// 375.073 us; speedup vs baseline: 2.9989x; 2.9989x over previous
//
#include <hip/hip_runtime.h>
#include <stdint.h>
#include <math.h>

#define NB 4
#define NU 1024
#define NS 256
#define NF 16
#define ND 256
#define NEGV -1000000000.0f
#define VBIT (1 << 14)
#define AGENT __HIP_MEMORY_SCOPE_AGENT
#define SPINCAP (1 << 20)
#define NGRP 32            // blocks per batch
#define SPB 8              // servers per block

// ctrl layout (unsigned words):
//   [32*b]                 rel[b]      release word, batch b (128B padded)
//   [256], [257]           det[2]      connect dtype detection
//   [1024 + (b*32+g)*32]   arrive slot per block (128B padded)

// ---------- detect connect dtype (int32 / float32 / byte), parallel ----------
__global__ __launch_bounds__(256) void k_detect(const uint8_t* __restrict__ conn,
                                                unsigned* __restrict__ det) {
  int i = blockIdx.x * 256 + threadIdx.x;
  uchar4 v = ((const uchar4*)conn)[i];
  bool c0 = v.x != 0;
  bool c123 = (v.y | v.z | v.w) != 0;
  unsigned long long m0 = __ballot(c0);
  unsigned long long m1 = __ballot(c123);
  if ((threadIdx.x & 63) == 0) {
    if (m0) atomicOr(&det[0], 1u);
    if (m1) atomicOr(&det[1], 1u);
  }
}

// ---------- transpose connect -> bitmask [b][s][u/32], coalesced via LDS ----------
__global__ __launch_bounds__(256) void k_transpose(const uint8_t* __restrict__ conn,
                                                   const unsigned* __restrict__ det,
                                                   uint32_t* __restrict__ connT) {
  unsigned d0 = det[0], d1 = det[1];
  int f = (d1 == 0) ? 0 : ((d0 == 0) ? 1 : 2);
  int blk = blockIdx.x;          // b*32 + ug ; 128 blocks
  int b = blk >> 5, ug = blk & 31;
  int u0 = ug * 32;
  int t = threadIdx.x;
  __shared__ uint8_t sm[32][260];
#pragma unroll 4
  for (int r = 0; r < 32; ++r) {
    int e = (b * NU + u0 + r) * NS + t;
    bool nz;
    if (f == 0)      nz = ((const int*)conn)[e] != 0;
    else if (f == 1) nz = ((const float*)conn)[e] != 0.0f;
    else             nz = conn[e] != 0;
    sm[r][t] = nz ? 1 : 0;
  }
  __syncthreads();
  uint32_t word = 0;
#pragma unroll
  for (int j = 0; j < 32; ++j) word |= (uint32_t)sm[j][t] << j;
  connT[(b * NS + t) * 32 + ug] = word;
}

// ---------- WS_K[d][c] = sum_e W_k[d][e] * W_state[e][c] ----------
__global__ __launch_bounds__(256) void k_weights(const float* __restrict__ W_state,
                                                 const float* __restrict__ W_k,
                                                 float* __restrict__ WS_K) {
  int d = threadIdx.x;
  const float4* wk4 = (const float4*)(W_k + d * ND);
  const float4* ws4 = (const float4*)W_state;
  float a0 = 0, a1 = 0, a2 = 0, a3 = 0;
  for (int e4 = 0; e4 < ND / 4; ++e4) {
    float4 k4 = wk4[e4];
    float4 w0 = ws4[e4 * 4 + 0];
    a0 += k4.x * w0.x; a1 += k4.x * w0.y; a2 += k4.x * w0.z; a3 += k4.x * w0.w;
    float4 w1 = ws4[e4 * 4 + 1];
    a0 += k4.y * w1.x; a1 += k4.y * w1.y; a2 += k4.y * w1.z; a3 += k4.y * w1.w;
    float4 w2 = ws4[e4 * 4 + 2];
    a0 += k4.z * w2.x; a1 += k4.z * w2.y; a2 += k4.z * w2.z; a3 += k4.z * w2.w;
    float4 w3 = ws4[e4 * 4 + 3];
    a0 += k4.w * w3.x; a1 += k4.w * w3.y; a2 += k4.w * w3.z; a3 += k4.w * w3.w;
  }
  ((float4*)WS_K)[d] = make_float4(a0, a1, a2, a3);
}

// ---------- f32 GEMM, double-buffered LDS (accumulation order bit-identical) ----------
__global__ __launch_bounds__(256) void k_gemm(
    const float* __restrict__ A, const float* __restrict__ Bm, float* __restrict__ C,
    int K, int lda, int ldb, int ldc, long sA, long sB, long sC,
    const float* __restrict__ biasA, float alpha) {
  int z = blockIdx.z;
  A += (size_t)z * sA; Bm += (size_t)z * sB; C += (size_t)z * sC;
  int m0 = blockIdx.y * 64, n0 = blockIdx.x * 64;
  int t = threadIdx.x;
  int tx = t & 15, ty = t >> 4;
  __shared__ float As[2][16][68];
  __shared__ float Bs[2][16][68];
  float acc[4][4];
#pragma unroll
  for (int i = 0; i < 4; i++)
#pragma unroll
    for (int j = 0; j < 4; j++) acc[i][j] = 0.f;
  int lr = t >> 2;
  int kq = (t & 3) * 4;
  {
    float4 av = *(const float4*)(A + (size_t)(m0 + lr) * lda + kq);
    if (biasA) {
      const float* bp = biasA + kq;
      av.x += bp[0]; av.y += bp[1]; av.z += bp[2]; av.w += bp[3];
    }
    As[0][kq + 0][lr] = av.x; As[0][kq + 1][lr] = av.y;
    As[0][kq + 2][lr] = av.z; As[0][kq + 3][lr] = av.w;
    float4 bv = *(const float4*)(Bm + (size_t)(n0 + lr) * ldb + kq);
    Bs[0][kq + 0][lr] = bv.x; Bs[0][kq + 1][lr] = bv.y;
    Bs[0][kq + 2][lr] = bv.z; Bs[0][kq + 3][lr] = bv.w;
  }
  __syncthreads();
  int nt = K >> 4;
  for (int ti = 0; ti < nt; ++ti) {
    int buf = ti & 1;
    float4 av2, bv2;
    bool more = (ti + 1 < nt);
    if (more) {
      int k0 = (ti + 1) << 4;
      av2 = *(const float4*)(A + (size_t)(m0 + lr) * lda + k0 + kq);
      if (biasA) {
        const float* bp = biasA + k0 + kq;
        av2.x += bp[0]; av2.y += bp[1]; av2.z += bp[2]; av2.w += bp[3];
      }
      bv2 = *(const float4*)(Bm + (size_t)(n0 + lr) * ldb + k0 + kq);
    }
#pragma unroll
    for (int k = 0; k < 16; ++k) {
      float4 a = *(const float4*)&As[buf][k][ty * 4];
      float4 bb = *(const float4*)&Bs[buf][k][tx * 4];
      float am[4] = {a.x, a.y, a.z, a.w};
      float bn[4] = {bb.x, bb.y, bb.z, bb.w};
#pragma unroll
      for (int i = 0; i < 4; ++i)
#pragma unroll
        for (int j = 0; j < 4; ++j) acc[i][j] += am[i] * bn[j];
    }
    if (more) {
      __syncthreads();
      int nb = buf ^ 1;
      As[nb][kq + 0][lr] = av2.x; As[nb][kq + 1][lr] = av2.y;
      As[nb][kq + 2][lr] = av2.z; As[nb][kq + 3][lr] = av2.w;
      Bs[nb][kq + 0][lr] = bv2.x; Bs[nb][kq + 1][lr] = bv2.y;
      Bs[nb][kq + 2][lr] = bv2.z; Bs[nb][kq + 3][lr] = bv2.w;
      __syncthreads();
    }
  }
#pragma unroll
  for (int i = 0; i < 4; ++i) {
    float4 o = make_float4(acc[i][0] * alpha, acc[i][1] * alpha,
                           acc[i][2] * alpha, acc[i][3] * alpha);
    *(float4*)(C + (size_t)(m0 + ty * 4 + i) * ldc + n0 + tx * 4) = o;
  }
}

// ---------- qc[bu][c] = inv_sqrt_d * sum_d q[bu][d] * WS_K[d][c], wave per row ----------
__global__ __launch_bounds__(256) void k_qc(const float* __restrict__ q,
                                            const float* __restrict__ WS_K,
                                            float* __restrict__ qc) {
  int row = blockIdx.x * 4 + (threadIdx.x >> 6);
  int ln = threadIdx.x & 63;
  const float* qr = q + (size_t)row * ND;
  float a0 = 0, a1 = 0, a2 = 0, a3 = 0;
  for (int d = ln; d < ND; d += 64) {
    float qv = qr[d];
    float4 w = ((const float4*)WS_K)[d];
    a0 += qv * w.x; a1 += qv * w.y; a2 += qv * w.z; a3 += qv * w.w;
  }
  for (int o = 32; o; o >>= 1) {
    a0 += __shfl_xor(a0, o); a1 += __shfl_xor(a1, o);
    a2 += __shfl_xor(a2, o); a3 += __shfl_xor(a3, o);
  }
  if (ln == 0)
    ((float4*)qc)[row] = make_float4(a0 * 0.0625f, a1 * 0.0625f, a2 * 0.0625f, a3 * 0.0625f);
}

// ---------- the 32-step allocator: 8 servers per block, 32 blocks per batch ----------
__global__ __launch_bounds__(256) void k_steps8(
    const float* __restrict__ L0T, const float* __restrict__ qc,
    const float* __restrict__ users, const float* __restrict__ servers,
    const uint32_t* __restrict__ connT, const float* __restrict__ fd_onehot,
    const float* __restrict__ W_us, const float* __restrict__ fd_alpha,
    const float* __restrict__ fd_beta, const float* __restrict__ score_bias,
    unsigned long long* __restrict__ propA, unsigned long long* __restrict__ propB,
    unsigned* __restrict__ ctrl,
    uint32_t* __restrict__ allocW, float* __restrict__ capF, float* __restrict__ out) {
  __shared__ float redM[SPB][256];
  __shared__ int redA[SPB][256];
  __shared__ unsigned keyEnc[NU];
  __shared__ unsigned srvMin[NU];
  __shared__ float lsum[NU];
  __shared__ uint32_t fdSh[NU];
  __shared__ float4 capS4[SPB];
  __shared__ float4 crS4[SPB];
  __shared__ float4 minv4[SPB];
  __shared__ int fidS[SPB];
  __shared__ float bM[SPB];
  __shared__ int bA[SPB];
  __shared__ float wredL[4];
  __shared__ int nr, sAny;

  const int blk = blockIdx.x;
  const int b = blk >> 5;         // batch
  const int g = blk & 31;         // group (servers g*8 .. g*8+7)
  const int tid = threadIdx.x;
  const int wv = tid >> 6, ln64 = tid & 63;
  const int sg = tid >> 5, ln = tid & 31;
  const int bs0 = b * NS + g * SPB;

  unsigned* rel = ctrl + 32 * b;
  unsigned* arrive = ctrl + 1024;

  const float a_ = fd_alpha[0], be_ = fd_beta[0];
  const float t0 = tanhf(be_), t1 = tanhf(a_ + be_);
  const float sb = score_bias[0];
  const float w0 = W_us[0], w1 = W_us[1], w2 = W_us[2];

  if (tid < SPB) {
    int srow = bs0 + tid;
    int f = 0;
    for (int ff = 0; ff < NF; ++ff)
      if (fd_onehot[srow * NF + ff] > 0.5f) { f = ff; break; }
    fidS[tid] = f;
    float4 ic = make_float4(servers[srow * 8 + 3], servers[srow * 8 + 4],
                            servers[srow * 8 + 5], servers[srow * 8 + 6]);
    capS4[tid] = ic;
    minv4[tid] = make_float4(fmaxf(ic.x, 1e-6f), fmaxf(ic.y, 1e-6f),
                             fmaxf(ic.z, 1e-6f), fmaxf(ic.w, 1e-6f));
  }

  // per-thread user state (users tid, tid+256, tid+512, tid+768 of batch b)
  float qc0[4], qc1[4], qc2[4], qc3[4], nax[4], nay[4], nbx[4], nby[4];
  float L0r[SPB][4];
  uint32_t upk[4] = {0, 0, 0, 0};   // bits 0-15 fdmask, bits 16-17 rc
  float usv[4];
  float logpv[4] = {0, 0, 0, 0};
  uint32_t cb = 0, ab = 0;          // bit (s*4+it): conn / alloc for own servers
#pragma unroll
  for (int it = 0; it < 4; ++it) {
    int u = it * 256 + tid, gu = b * NU + u;
    float4 q4 = *(const float4*)(qc + gu * 4);
    qc0[it] = q4.x; qc1[it] = q4.y; qc2[it] = q4.z; qc3[it] = q4.w;
    float2 nA = *(const float2*)(users + gu * 8 + 2);
    float2 nB2 = *(const float2*)(users + gu * 8 + 4);
    nax[it] = nA.x; nay[it] = nA.y; nbx[it] = nB2.x; nby[it] = nB2.y;
    usv[it] = w1;
  }
#pragma unroll
  for (int s = 0; s < SPB; ++s)
#pragma unroll
    for (int it = 0; it < 4; ++it) {
      L0r[s][it] = L0T[(size_t)(bs0 + s) * NU + it * 256 + tid];
      uint32_t word = connT[(bs0 + s) * 32 + it * 8 + (tid >> 5)];
      cb |= ((word >> (tid & 31)) & 1u) << (s * 4 + it);
    }
  for (int i = tid; i < NU; i += 256) {
    keyEnc[i] = 0u; srvMin[i] = 0xFFFFFFFFu; lsum[i] = 0.f; fdSh[i] = 0u;
  }
  __syncthreads();

  for (int step = 0; step < 32; ++step) {
    // ---- cr per server ----
    if (tid < SPB) {
      float4 c = capS4[tid];
      float4 mv = minv4[tid];
      crS4[tid] = make_float4(c.x / mv.x, c.y / mv.y, c.z / mv.z, c.w / mv.w);
    }
    __syncthreads();

    // ---- phase A: per-thread best over own 4 users for each of 8 servers ----
    float cand[SPB][4];
#pragma unroll
    for (int s = 0; s < SPB; ++s) {
      float4 c = capS4[s];
      float4 cr = crS4[s];
      int fid = fidS[s];
      float m = NEGV; int a = 0x7fffffff;
#pragma unroll
      for (int it = 0; it < 4; ++it) {
        int u = it * 256 + tid;
        bool el = ((cb >> (s * 4 + it)) & 1u) && !((ab >> (s * 4 + it)) & 1u) &&
                  ((upk[it] & 0x30000u) != 0x30000u) &&
                  c.x >= nax[it] && c.y >= nay[it] && c.z >= nbx[it] && c.w >= nby[it];
        float tt = ((upk[it] >> fid) & 1u) ? t0 : t1;
        float lg = L0r[s][it] + qc0[it] * cr.x + qc1[it] * cr.y + qc2[it] * cr.z +
                   qc3[it] * cr.w + sb + tt + usv[it];
        float cv = el ? lg : NEGV;
        cand[s][it] = cv;
        if (cv > m || (cv == m && u < a)) { m = cv; a = u; }
      }
      redM[s][tid] = m; redA[s][tid] = a;
    }
    __syncthreads();
    // 32-lane group sg reduces server sg over all 256 threads
    {
      float m = redM[sg][ln * 8]; int a = redA[sg][ln * 8];
#pragma unroll
      for (int j = 1; j < 8; ++j) {
        float v = redM[sg][ln * 8 + j]; int aa = redA[sg][ln * 8 + j];
        if (v > m || (v == m && aa < a)) { m = v; a = aa; }
      }
      for (int o = 16; o; o >>= 1) {
        float ov = __shfl_xor(m, o); int oa = __shfl_xor(a, o);
        if (ov > m || (ov == m && oa < a)) { m = ov; a = oa; }
      }
      if (ln == 0) { bM[sg] = m; bA[sg] = a; }
    }
    __syncthreads();
    // lse partials
#pragma unroll
    for (int s = 0; s < SPB; ++s) {
      float mv = bM[s];
      redM[s][tid] = expf(cand[s][0] - mv) + expf(cand[s][1] - mv) +
                     expf(cand[s][2] - mv) + expf(cand[s][3] - mv);
    }
    __syncthreads();
    {
      float ps = redM[sg][ln * 8];
#pragma unroll
      for (int j = 1; j < 8; ++j) ps += redM[sg][ln * 8 + j];
      for (int o = 16; o; o >>= 1) ps += __shfl_xor(ps, o);
      if (ln == 0) {
        float maxv = bM[sg]; int argu = bA[sg];
        unsigned validb = (maxv > -1e8f) ? VBIT : 0;
        unsigned pinfo = (unsigned)argu | ((unsigned)fidS[sg] << 10) | validb;
        unsigned long long A = (unsigned long long)pinfo |
                               ((unsigned long long)__float_as_uint(maxv) << 32);
        unsigned long long Bv = (unsigned long long)__float_as_uint(-logf(ps));
        int par = (step & 1) * (NB * NS);
        __hip_atomic_store(&propA[par + b * NS + g * SPB + sg], A, __ATOMIC_RELAXED, AGENT);
        __hip_atomic_store(&propB[par + b * NS + g * SPB + sg], Bv, __ATOMIC_RELAXED, AGENT);
      }
    }

    // ---- barrier over the batch's 32 blocks ----
    {
      unsigned e = (unsigned)(step + 1);
      asm volatile("s_waitcnt vmcnt(0)" ::: "memory");   // drain all waves' prop stores
      __syncthreads();
      if (g == 0) {
        bool ready = true;
        unsigned* slot = nullptr;
        if (tid > 0 && tid < 32) {
          slot = arrive + (unsigned)(b * 32 + tid) * 32u;
          ready = false;
        }
        int iters = 0;
        for (;;) {
          if (tid == 0) nr = 0;
          __syncthreads();
          if (!ready && __hip_atomic_load(slot, __ATOMIC_RELAXED, AGENT) >= e) ready = true;
          unsigned long long mm = __ballot(!ready);
          if (mm && (tid & 63) == 0) atomicOr(&nr, 1);
          __syncthreads();
          if (nr == 0 || ++iters > SPINCAP) break;
          __builtin_amdgcn_s_sleep(1);
        }
        if (tid == 0) __hip_atomic_store(rel, e, __ATOMIC_RELAXED, AGENT);
      } else if (tid == 0) {
        __hip_atomic_store(arrive + (unsigned)(b * 32 + g) * 32u, e, __ATOMIC_RELAXED, AGENT);
        int iters = 0;
        while (__hip_atomic_load(rel, __ATOMIC_RELAXED, AGENT) < e) {
          __builtin_amdgcn_s_sleep(2);
          if (++iters > SPINCAP) break;
        }
      }
      __syncthreads();
    }

    // ---- phase B: read all 256 proposals of the batch; resolve per-user winners ----
    {
      int par = (step & 1) * (NB * NS) + b * NS;
      unsigned long long A = __hip_atomic_load(&propA[par + tid], __ATOMIC_RELAXED, AGENT);
      unsigned pi = (unsigned)A;
      if (tid == 0) sAny = 0;
      __syncthreads();
      unsigned long long mm = __ballot((pi & VBIT) != 0);
      if (mm && (tid & 63) == 0) atomicOr(&sAny, 1);
      __syncthreads();
      if (sAny == 0) break;                   // batch frozen forever
      unsigned encv = 0;
      int pu = pi & 1023;
      if (pi & VBIT) {
        unsigned vb = (unsigned)(A >> 32);
        encv = (vb & 0x80000000u) ? ~vb : (vb | 0x80000000u);
        atomicMax(&keyEnc[pu], encv);
        unsigned long long Bv = __hip_atomic_load(&propB[par + tid], __ATOMIC_RELAXED, AGENT);
        atomicAdd(&lsum[pu], __uint_as_float((unsigned)Bv));
        atomicOr(&fdSh[pu], 1u << ((pi >> 10) & 15));
      }
      __syncthreads();
      if ((pi & VBIT) && keyEnc[pu] == encv)
        atomicMin(&srvMin[pu], (unsigned)tid);
      __syncthreads();
#pragma unroll
      for (int it = 0; it < 4; ++it) {
        int u = it * 256 + tid;
        unsigned ke = keyEnc[u];
        if (ke) {
          unsigned win = srvMin[u];
          logpv[it] += lsum[u];
          uint32_t fda = fdSh[u];
          keyEnc[u] = 0u; srvMin[u] = 0xFFFFFFFFu; lsum[u] = 0.f; fdSh[u] = 0u;
          uint32_t pk = upk[it];
          int r = (int)((pk >> 16) & 3) + 1;
          upk[it] = ((pk | fda) & 0xFFFFu) | ((uint32_t)r << 16);
          float rf = (float)r;
          usv[it] = w0 * (rf / 3.0f) + w1 * (fmaxf(3.0f - rf, 0.f) / 3.0f) +
                    ((r == 2) ? w2 : 0.f);
          if ((int)(win >> 3) == g) {
            int sl = win & 7;
            ab |= 1u << (sl * 4 + it);
            float4 c = capS4[sl];           // unique (server,step) winner -> no race
            capS4[sl] = make_float4(fmaxf(c.x - nax[it], 0.f), fmaxf(c.y - nay[it], 0.f),
                                    fmaxf(c.z - nbx[it], 0.f), fmaxf(c.w - nby[it], 0.f));
          }
        }
      }
      __syncthreads();
    }
  }

  // ---- outputs ----
#pragma unroll
  for (int s = 0; s < SPB; ++s)
#pragma unroll
    for (int it = 0; it < 4; ++it) {
      unsigned long long m = __ballot((ab >> (s * 4 + it)) & 1u);
      if (ln64 == 0)
        *(unsigned long long*)&allocW[(bs0 + s) * 32 + it * 8 + wv * 2] = m;
    }
  if (tid < SPB)
    *(float4*)(capF + (bs0 + tid) * 4) = capS4[tid];
  if (g == 0) {
    float a = logpv[0] + logpv[1] + logpv[2] + logpv[3];
    for (int o = 32; o; o >>= 1) a += __shfl_xor(a, o);
    if (ln64 == 0) wredL[wv] = a;
    __syncthreads();
    if (tid == 0) out[b] = wredL[0] + wredL[1] + wredL[2] + wredL[3];
  }
}

// ---------- expand bitmask + cap to output layout ----------
__global__ __launch_bounds__(256) void k_store(const uint32_t* __restrict__ allocW,
                                               const float* __restrict__ capF,
                                               float* __restrict__ out) {
  int blk = blockIdx.x;
  if (blk < 1024) {
    int i4 = (blk * 256 + threadIdx.x) * 4;
    int b = i4 >> 18;
    int u = (i4 >> 8) & 1023;
    int s = i4 & 255;
    int base = (b * NS + s) * 32 + (u >> 5);
    uint32_t bitm = 1u << (u & 31);
    float4 o;
    o.x = (allocW[base] & bitm) ? 1.f : 0.f;
    o.y = (allocW[base + 32] & bitm) ? 1.f : 0.f;
    o.z = (allocW[base + 64] & bitm) ? 1.f : 0.f;
    o.w = (allocW[base + 96] & bitm) ? 1.f : 0.f;
    *(float4*)(out + 4 + i4) = o;
  } else {
    int b = blk - 1024;
    int s = threadIdx.x;
    float4 c = *(const float4*)(capF + (b * NS + s) * 4);
    *(float4*)(out + 4 + NB * NU * NS + (b * NS + s) * 4) = c;
  }
}

extern "C" void kernel_launch(void* const* d_in, const int* in_sizes, int n_in,
                              void* d_out, int out_size, void* d_ws, size_t ws_size,
                              hipStream_t stream) {
  const float* user_enc = (const float*)d_in[0];
  const float* server_enc = (const float*)d_in[1];
  const float* users = (const float*)d_in[2];
  const float* servers = (const float*)d_in[3];
  const uint8_t* connect = (const uint8_t*)d_in[4];
  const float* fd_onehot = (const float*)d_in[5];
  const float* W_state = (const float*)d_in[6];
  const float* b_state = (const float*)d_in[7];
  const float* W_q = (const float*)d_in[8];
  const float* W_k = (const float*)d_in[9];
  const float* W_us = (const float*)d_in[10];
  const float* fd_alpha = (const float*)d_in[11];
  const float* fd_beta = (const float*)d_in[12];
  const float* score_bias = (const float*)d_in[13];

  char* ws = (char*)d_ws;
  size_t off = 0;
  auto take = [&](size_t bytes) -> void* {
    size_t cur = off;
    off = (off + bytes + 255) & ~(size_t)255;
    return (void*)(ws + cur);
  };
  const size_t ctrlBytes = (size_t)(1024 + NB * NGRP * 32) * 4;   // 20 KB
  unsigned* ctrl = (unsigned*)take(ctrlBytes);
  unsigned* det = ctrl + 256;
  float* q = (float*)take((size_t)NB * NU * ND * 4);
  float* kb = (float*)take((size_t)NB * NS * ND * 4);
  float* L0T = (float*)take((size_t)NB * NS * NU * 4);
  float* qc = (float*)take((size_t)NB * NU * 4 * 4);
  float* WS_K = (float*)take((size_t)ND * 4 * 4);
  uint32_t* connT = (uint32_t*)take((size_t)NB * NS * 32 * 4);
  unsigned long long* propA = (unsigned long long*)take((size_t)2 * NB * NS * 8);
  unsigned long long* propB = (unsigned long long*)take((size_t)2 * NB * NS * 8);
  uint32_t* allocW = (uint32_t*)take((size_t)NB * NS * 32 * 4);
  float* capF = (float*)take((size_t)NB * NS * 4 * 4);
  float* outp = (float*)d_out;

  hipMemsetAsync(ctrl, 0, ctrlBytes, stream);
  k_detect<<<64, 256, 0, stream>>>(connect, det);
  k_transpose<<<128, 256, 0, stream>>>(connect, det, connT);
  k_weights<<<1, 256, 0, stream>>>(W_state, W_k, WS_K);
  k_gemm<<<dim3(ND / 64, (NB * NU) / 64, 1), 256, 0, stream>>>(
      user_enc, W_q, q, ND, ND, ND, ND, 0, 0, 0, nullptr, 1.f);
  k_gemm<<<dim3(ND / 64, (NB * NS) / 64, 1), 256, 0, stream>>>(
      server_enc, W_k, kb, ND, ND, ND, ND, 0, 0, 0, b_state, 1.f);
  k_qc<<<NB * NU / 4, 256, 0, stream>>>(q, WS_K, qc);
  k_gemm<<<dim3(NU / 64, NS / 64, NB), 256, 0, stream>>>(
      kb, q, L0T, ND, ND, ND, NU,
      (long)NS * ND, (long)NU * ND, (long)NS * NU, nullptr, 0.0625f);

  // 128 blocks <= 256 CUs: co-residency guaranteed unconditionally -> no fallback
  k_steps8<<<dim3(NB * NGRP), dim3(256), 0, stream>>>(
      L0T, qc, users, servers, connT, fd_onehot, W_us, fd_alpha, fd_beta, score_bias,
      propA, propB, ctrl, allocW, capF, outp);

  k_store<<<1028, 256, 0, stream>>>(allocW, capF, (float*)d_out);
}

// Round 9
// 291.311 us; speedup vs baseline: 3.8612x; 1.2875x over previous
//
#include <hip/hip_runtime.h>
#include <stdint.h>
#include <math.h>

#define NB 4
#define NU 1024
#define NS 256
#define NF 16
#define ND 256
#define NEGV -1000000000.0f
#define VBIT (1 << 14)
#define AGENT __HIP_MEMORY_SCOPE_AGENT
#define SPINCAP (1 << 20)
#define NGRP 64            // blocks per batch
#define SPB 4              // servers per block

// ctrl layout (unsigned words):
//   [256], [257]           det[2]      connect dtype detection
//   [1024 + (b*64+g)*32]   arrive slot per block (128B padded)

// ---------- detect connect dtype (int32 / float32 / byte), parallel ----------
__global__ __launch_bounds__(256) void k_detect(const uint8_t* __restrict__ conn,
                                                unsigned* __restrict__ det) {
  int i = blockIdx.x * 256 + threadIdx.x;
  uchar4 v = ((const uchar4*)conn)[i];
  bool c0 = v.x != 0;
  bool c123 = (v.y | v.z | v.w) != 0;
  unsigned long long m0 = __ballot(c0);
  unsigned long long m1 = __ballot(c123);
  if ((threadIdx.x & 63) == 0) {
    if (m0) atomicOr(&det[0], 1u);
    if (m1) atomicOr(&det[1], 1u);
  }
}

// ---------- transpose connect -> bitmask [b][s][u/32], coalesced via LDS ----------
__global__ __launch_bounds__(256) void k_transpose(const uint8_t* __restrict__ conn,
                                                   const unsigned* __restrict__ det,
                                                   uint32_t* __restrict__ connT) {
  unsigned d0 = det[0], d1 = det[1];
  int f = (d1 == 0) ? 0 : ((d0 == 0) ? 1 : 2);
  int blk = blockIdx.x;          // b*32 + ug ; 128 blocks
  int b = blk >> 5, ug = blk & 31;
  int u0 = ug * 32;
  int t = threadIdx.x;
  __shared__ uint8_t sm[32][260];
#pragma unroll 4
  for (int r = 0; r < 32; ++r) {
    int e = (b * NU + u0 + r) * NS + t;
    bool nz;
    if (f == 0)      nz = ((const int*)conn)[e] != 0;
    else if (f == 1) nz = ((const float*)conn)[e] != 0.0f;
    else             nz = conn[e] != 0;
    sm[r][t] = nz ? 1 : 0;
  }
  __syncthreads();
  uint32_t word = 0;
#pragma unroll
  for (int j = 0; j < 32; ++j) word |= (uint32_t)sm[j][t] << j;
  connT[(b * NS + t) * 32 + ug] = word;
}

// ---------- WS_K[d][c] = sum_e W_k[d][e] * W_state[e][c] ----------
__global__ __launch_bounds__(256) void k_weights(const float* __restrict__ W_state,
                                                 const float* __restrict__ W_k,
                                                 float* __restrict__ WS_K) {
  int d = threadIdx.x;
  const float4* wk4 = (const float4*)(W_k + d * ND);
  const float4* ws4 = (const float4*)W_state;
  float a0 = 0, a1 = 0, a2 = 0, a3 = 0;
  for (int e4 = 0; e4 < ND / 4; ++e4) {
    float4 k4 = wk4[e4];
    float4 w0 = ws4[e4 * 4 + 0];
    a0 += k4.x * w0.x; a1 += k4.x * w0.y; a2 += k4.x * w0.z; a3 += k4.x * w0.w;
    float4 w1 = ws4[e4 * 4 + 1];
    a0 += k4.y * w1.x; a1 += k4.y * w1.y; a2 += k4.y * w1.z; a3 += k4.y * w1.w;
    float4 w2 = ws4[e4 * 4 + 2];
    a0 += k4.z * w2.x; a1 += k4.z * w2.y; a2 += k4.z * w2.z; a3 += k4.z * w2.w;
    float4 w3 = ws4[e4 * 4 + 3];
    a0 += k4.w * w3.x; a1 += k4.w * w3.y; a2 += k4.w * w3.z; a3 += k4.w * w3.w;
  }
  ((float4*)WS_K)[d] = make_float4(a0, a1, a2, a3);
}

// ---------- f32 GEMM, double-buffered LDS (accumulation order bit-identical) ----------
__global__ __launch_bounds__(256) void k_gemm(
    const float* __restrict__ A, const float* __restrict__ Bm, float* __restrict__ C,
    int K, int lda, int ldb, int ldc, long sA, long sB, long sC,
    const float* __restrict__ biasA, float alpha) {
  int z = blockIdx.z;
  A += (size_t)z * sA; Bm += (size_t)z * sB; C += (size_t)z * sC;
  int m0 = blockIdx.y * 64, n0 = blockIdx.x * 64;
  int t = threadIdx.x;
  int tx = t & 15, ty = t >> 4;
  __shared__ float As[2][16][68];
  __shared__ float Bs[2][16][68];
  float acc[4][4];
#pragma unroll
  for (int i = 0; i < 4; i++)
#pragma unroll
    for (int j = 0; j < 4; j++) acc[i][j] = 0.f;
  int lr = t >> 2;
  int kq = (t & 3) * 4;
  {
    float4 av = *(const float4*)(A + (size_t)(m0 + lr) * lda + kq);
    if (biasA) {
      const float* bp = biasA + kq;
      av.x += bp[0]; av.y += bp[1]; av.z += bp[2]; av.w += bp[3];
    }
    As[0][kq + 0][lr] = av.x; As[0][kq + 1][lr] = av.y;
    As[0][kq + 2][lr] = av.z; As[0][kq + 3][lr] = av.w;
    float4 bv = *(const float4*)(Bm + (size_t)(n0 + lr) * ldb + kq);
    Bs[0][kq + 0][lr] = bv.x; Bs[0][kq + 1][lr] = bv.y;
    Bs[0][kq + 2][lr] = bv.z; Bs[0][kq + 3][lr] = bv.w;
  }
  __syncthreads();
  int nt = K >> 4;
  for (int ti = 0; ti < nt; ++ti) {
    int buf = ti & 1;
    float4 av2, bv2;
    bool more = (ti + 1 < nt);
    if (more) {
      int k0 = (ti + 1) << 4;
      av2 = *(const float4*)(A + (size_t)(m0 + lr) * lda + k0 + kq);
      if (biasA) {
        const float* bp = biasA + k0 + kq;
        av2.x += bp[0]; av2.y += bp[1]; av2.z += bp[2]; av2.w += bp[3];
      }
      bv2 = *(const float4*)(Bm + (size_t)(n0 + lr) * ldb + k0 + kq);
    }
#pragma unroll
    for (int k = 0; k < 16; ++k) {
      float4 a = *(const float4*)&As[buf][k][ty * 4];
      float4 bb = *(const float4*)&Bs[buf][k][tx * 4];
      float am[4] = {a.x, a.y, a.z, a.w};
      float bn[4] = {bb.x, bb.y, bb.z, bb.w};
#pragma unroll
      for (int i = 0; i < 4; ++i)
#pragma unroll
        for (int j = 0; j < 4; ++j) acc[i][j] += am[i] * bn[j];
    }
    if (more) {
      __syncthreads();
      int nb = buf ^ 1;
      As[nb][kq + 0][lr] = av2.x; As[nb][kq + 1][lr] = av2.y;
      As[nb][kq + 2][lr] = av2.z; As[nb][kq + 3][lr] = av2.w;
      Bs[nb][kq + 0][lr] = bv2.x; Bs[nb][kq + 1][lr] = bv2.y;
      Bs[nb][kq + 2][lr] = bv2.z; Bs[nb][kq + 3][lr] = bv2.w;
      __syncthreads();
    }
  }
#pragma unroll
  for (int i = 0; i < 4; ++i) {
    float4 o = make_float4(acc[i][0] * alpha, acc[i][1] * alpha,
                           acc[i][2] * alpha, acc[i][3] * alpha);
    *(float4*)(C + (size_t)(m0 + ty * 4 + i) * ldc + n0 + tx * 4) = o;
  }
}

// ---------- qc[bu][c] = inv_sqrt_d * sum_d q[bu][d] * WS_K[d][c], wave per row ----------
__global__ __launch_bounds__(256) void k_qc(const float* __restrict__ q,
                                            const float* __restrict__ WS_K,
                                            float* __restrict__ qc) {
  int row = blockIdx.x * 4 + (threadIdx.x >> 6);
  int ln = threadIdx.x & 63;
  const float* qr = q + (size_t)row * ND;
  float a0 = 0, a1 = 0, a2 = 0, a3 = 0;
  for (int d = ln; d < ND; d += 64) {
    float qv = qr[d];
    float4 w = ((const float4*)WS_K)[d];
    a0 += qv * w.x; a1 += qv * w.y; a2 += qv * w.z; a3 += qv * w.w;
  }
  for (int o = 32; o; o >>= 1) {
    a0 += __shfl_xor(a0, o); a1 += __shfl_xor(a1, o);
    a2 += __shfl_xor(a2, o); a3 += __shfl_xor(a3, o);
  }
  if (ln == 0)
    ((float4*)qc)[row] = make_float4(a0 * 0.0625f, a1 * 0.0625f, a2 * 0.0625f, a3 * 0.0625f);
}

// ---------- the 32-step allocator: 4 servers per block, 64 blocks per batch ----------
__global__ __launch_bounds__(256) void k_steps4(
    const float* __restrict__ L0T, const float* __restrict__ qc,
    const float* __restrict__ users, const float* __restrict__ servers,
    const uint32_t* __restrict__ connT, const float* __restrict__ fd_onehot,
    const float* __restrict__ W_us, const float* __restrict__ fd_alpha,
    const float* __restrict__ fd_beta, const float* __restrict__ score_bias,
    unsigned long long* __restrict__ propA, unsigned long long* __restrict__ propB,
    unsigned* __restrict__ ctrl,
    uint32_t* __restrict__ allocW, float* __restrict__ capF, float* __restrict__ out) {
  __shared__ float redM[SPB][256];
  __shared__ int redA[SPB][256];
  __shared__ unsigned keyEnc[NU];
  __shared__ unsigned srvMin[NU];
  __shared__ float lsum[NU];
  __shared__ uint32_t fdSh[NU];
  __shared__ float4 capS4[SPB];
  __shared__ float4 crS4[SPB];
  __shared__ float4 minv4[SPB];
  __shared__ int fidS[SPB];
  __shared__ float bM[SPB];
  __shared__ int bA[SPB];
  __shared__ float wredL[4];
  __shared__ int sAny;

  const int blk = blockIdx.x;
  const int b = blk >> 6;         // batch
  const int g = blk & 63;         // group (servers g*4 .. g*4+3)
  const int tid = threadIdx.x;
  const int wv = tid >> 6, ln64 = tid & 63;
  const int sg = tid >> 6;        // server group (0..3), 64 lanes each
  const int bs0 = b * NS + g * SPB;

  unsigned* arrive = ctrl + 1024;

  const float a_ = fd_alpha[0], be_ = fd_beta[0];
  const float t0 = tanhf(be_), t1 = tanhf(a_ + be_);
  const float sb = score_bias[0];
  const float w0 = W_us[0], w1 = W_us[1], w2 = W_us[2];

  if (tid < SPB) {
    int srow = bs0 + tid;
    int f = 0;
    for (int ff = 0; ff < NF; ++ff)
      if (fd_onehot[srow * NF + ff] > 0.5f) { f = ff; break; }
    fidS[tid] = f;
    float4 ic = make_float4(servers[srow * 8 + 3], servers[srow * 8 + 4],
                            servers[srow * 8 + 5], servers[srow * 8 + 6]);
    capS4[tid] = ic;
    minv4[tid] = make_float4(fmaxf(ic.x, 1e-6f), fmaxf(ic.y, 1e-6f),
                             fmaxf(ic.z, 1e-6f), fmaxf(ic.w, 1e-6f));
  }

  // per-thread user state (users tid, tid+256, tid+512, tid+768 of batch b)
  float qc0[4], qc1[4], qc2[4], qc3[4], nax[4], nay[4], nbx[4], nby[4];
  float L0r[SPB][4];
  uint32_t upk[4] = {0, 0, 0, 0};   // bits 0-15 fdmask, bits 16-17 rc
  float usv[4];
  float logpv[4] = {0, 0, 0, 0};
  uint32_t cb = 0, ab = 0;          // bit (s*4+it): conn / alloc for own servers
#pragma unroll
  for (int it = 0; it < 4; ++it) {
    int u = it * 256 + tid, gu = b * NU + u;
    float4 q4 = *(const float4*)(qc + gu * 4);
    qc0[it] = q4.x; qc1[it] = q4.y; qc2[it] = q4.z; qc3[it] = q4.w;
    float2 nA = *(const float2*)(users + gu * 8 + 2);
    float2 nB2 = *(const float2*)(users + gu * 8 + 4);
    nax[it] = nA.x; nay[it] = nA.y; nbx[it] = nB2.x; nby[it] = nB2.y;
    usv[it] = w1;
  }
#pragma unroll
  for (int s = 0; s < SPB; ++s)
#pragma unroll
    for (int it = 0; it < 4; ++it) {
      L0r[s][it] = L0T[(size_t)(bs0 + s) * NU + it * 256 + tid];
      uint32_t word = connT[(bs0 + s) * 32 + it * 8 + (tid >> 5)];
      cb |= ((word >> (tid & 31)) & 1u) << (s * 4 + it);
    }
  for (int i = tid; i < NU; i += 256) {
    keyEnc[i] = 0u; srvMin[i] = 0xFFFFFFFFu; lsum[i] = 0.f; fdSh[i] = 0u;
  }
  __syncthreads();

  for (int step = 0; step < 32; ++step) {
    if (tid < SPB) {
      float4 c = capS4[tid];
      float4 mv = minv4[tid];
      crS4[tid] = make_float4(c.x / mv.x, c.y / mv.y, c.z / mv.z, c.w / mv.w);
    }
    __syncthreads();

    // ---- phase A: per-thread best over own 4 users for each of 4 servers ----
    float cand[SPB][4];
#pragma unroll
    for (int s = 0; s < SPB; ++s) {
      float4 c = capS4[s];
      float4 cr = crS4[s];
      int fid = fidS[s];
      float m = NEGV; int a = 0x7fffffff;
#pragma unroll
      for (int it = 0; it < 4; ++it) {
        int u = it * 256 + tid;
        bool el = ((cb >> (s * 4 + it)) & 1u) && !((ab >> (s * 4 + it)) & 1u) &&
                  ((upk[it] & 0x30000u) != 0x30000u) &&
                  c.x >= nax[it] && c.y >= nay[it] && c.z >= nbx[it] && c.w >= nby[it];
        float tt = ((upk[it] >> fid) & 1u) ? t0 : t1;
        float lg = L0r[s][it] + qc0[it] * cr.x + qc1[it] * cr.y + qc2[it] * cr.z +
                   qc3[it] * cr.w + sb + tt + usv[it];
        float cv = el ? lg : NEGV;
        cand[s][it] = cv;
        if (cv > m || (cv == m && u < a)) { m = cv; a = u; }
      }
      redM[s][tid] = m; redA[s][tid] = a;
    }
    __syncthreads();
    // 64-lane group sg reduces server sg over all 256 threads
    {
      int ln = ln64;
      float m = redM[sg][ln * 4]; int a = redA[sg][ln * 4];
#pragma unroll
      for (int j = 1; j < 4; ++j) {
        float v = redM[sg][ln * 4 + j]; int aa = redA[sg][ln * 4 + j];
        if (v > m || (v == m && aa < a)) { m = v; a = aa; }
      }
      for (int o = 32; o; o >>= 1) {
        float ov = __shfl_xor(m, o); int oa = __shfl_xor(a, o);
        if (ov > m || (ov == m && oa < a)) { m = ov; a = oa; }
      }
      if (ln == 0) { bM[sg] = m; bA[sg] = a; }
    }
    __syncthreads();
    // lse partials
#pragma unroll
    for (int s = 0; s < SPB; ++s) {
      float mv = bM[s];
      redM[s][tid] = expf(cand[s][0] - mv) + expf(cand[s][1] - mv) +
                     expf(cand[s][2] - mv) + expf(cand[s][3] - mv);
    }
    __syncthreads();
    {
      int ln = ln64;
      float ps = redM[sg][ln * 4];
#pragma unroll
      for (int j = 1; j < 4; ++j) ps += redM[sg][ln * 4 + j];
      for (int o = 32; o; o >>= 1) ps += __shfl_xor(ps, o);
      if (ln == 0) {
        float maxv = bM[sg]; int argu = bA[sg];
        unsigned validb = (maxv > -1e8f) ? VBIT : 0;
        unsigned pinfo = (unsigned)argu | ((unsigned)fidS[sg] << 10) | validb;
        unsigned long long A = (unsigned long long)pinfo |
                               ((unsigned long long)__float_as_uint(maxv) << 32);
        unsigned long long Bv = (unsigned long long)__float_as_uint(-logf(ps));
        int par = (step & 1) * (NB * NS);
        __hip_atomic_store(&propA[par + bs0 + sg], A, __ATOMIC_RELAXED, AGENT);
        __hip_atomic_store(&propB[par + bs0 + sg], Bv, __ATOMIC_RELAXED, AGENT);
      }
    }

    // ---- one-hop all-to-all barrier over the batch's 64 blocks ----
    {
      unsigned e = (unsigned)(step + 1);
      asm volatile("s_waitcnt vmcnt(0)" ::: "memory");   // each wave drains its stores
      __syncthreads();                                    // all waves drained
      if (tid == 0)
        __hip_atomic_store(arrive + (unsigned)(b * 64 + g) * 32u, e,
                           __ATOMIC_RELAXED, AGENT);
      if (tid < 64) {
        unsigned* slot = arrive + (unsigned)(b * 64 + tid) * 32u;
        int iters = 0;
        while (__hip_atomic_load(slot, __ATOMIC_RELAXED, AGENT) < e) {
          __builtin_amdgcn_s_sleep(1);
          if (++iters > SPINCAP) break;
        }
      }
      __syncthreads();
    }

    // ---- phase B: read all 256 proposals of the batch; resolve per-user winners ----
    {
      int par = (step & 1) * (NB * NS) + b * NS;
      unsigned long long A = __hip_atomic_load(&propA[par + tid], __ATOMIC_RELAXED, AGENT);
      unsigned pi = (unsigned)A;
      if (tid == 0) sAny = 0;
      __syncthreads();
      unsigned long long mm = __ballot((pi & VBIT) != 0);
      if (mm && (tid & 63) == 0) atomicOr(&sAny, 1);
      __syncthreads();
      if (sAny == 0) break;                   // batch frozen forever
      unsigned encv = 0;
      int pu = pi & 1023;
      if (pi & VBIT) {
        unsigned vb = (unsigned)(A >> 32);
        encv = (vb & 0x80000000u) ? ~vb : (vb | 0x80000000u);
        atomicMax(&keyEnc[pu], encv);
        unsigned long long Bv = __hip_atomic_load(&propB[par + tid], __ATOMIC_RELAXED, AGENT);
        atomicAdd(&lsum[pu], __uint_as_float((unsigned)Bv));
        atomicOr(&fdSh[pu], 1u << ((pi >> 10) & 15));
      }
      __syncthreads();
      if ((pi & VBIT) && keyEnc[pu] == encv)
        atomicMin(&srvMin[pu], (unsigned)tid);
      __syncthreads();
#pragma unroll
      for (int it = 0; it < 4; ++it) {
        int u = it * 256 + tid;
        unsigned ke = keyEnc[u];
        if (ke) {
          unsigned win = srvMin[u];
          logpv[it] += lsum[u];
          uint32_t fda = fdSh[u];
          keyEnc[u] = 0u; srvMin[u] = 0xFFFFFFFFu; lsum[u] = 0.f; fdSh[u] = 0u;
          uint32_t pk = upk[it];
          int r = (int)((pk >> 16) & 3) + 1;
          upk[it] = ((pk | fda) & 0xFFFFu) | ((uint32_t)r << 16);
          float rf = (float)r;
          usv[it] = w0 * (rf / 3.0f) + w1 * (fmaxf(3.0f - rf, 0.f) / 3.0f) +
                    ((r == 2) ? w2 : 0.f);
          if ((int)(win >> 2) == g) {
            int sl = win & 3;
            ab |= 1u << (sl * 4 + it);
            float4 c = capS4[sl];           // unique (server,step) winner -> no race
            capS4[sl] = make_float4(fmaxf(c.x - nax[it], 0.f), fmaxf(c.y - nay[it], 0.f),
                                    fmaxf(c.z - nbx[it], 0.f), fmaxf(c.w - nby[it], 0.f));
          }
        }
      }
      __syncthreads();
    }
  }

  // ---- outputs ----
#pragma unroll
  for (int s = 0; s < SPB; ++s)
#pragma unroll
    for (int it = 0; it < 4; ++it) {
      unsigned long long m = __ballot((ab >> (s * 4 + it)) & 1u);
      if (ln64 == 0)
        *(unsigned long long*)&allocW[(bs0 + s) * 32 + it * 8 + wv * 2] = m;
    }
  if (tid < SPB)
    *(float4*)(capF + (bs0 + tid) * 4) = capS4[tid];
  if (g == 0) {
    float a = logpv[0] + logpv[1] + logpv[2] + logpv[3];
    for (int o = 32; o; o >>= 1) a += __shfl_xor(a, o);
    if (ln64 == 0) wredL[wv] = a;
    __syncthreads();
    if (tid == 0) out[b] = wredL[0] + wredL[1] + wredL[2] + wredL[3];
  }
}

// ---------- expand bitmask + cap to output layout ----------
__global__ __launch_bounds__(256) void k_store(const uint32_t* __restrict__ allocW,
                                               const float* __restrict__ capF,
                                               float* __restrict__ out) {
  int blk = blockIdx.x;
  if (blk < 1024) {
    int i4 = (blk * 256 + threadIdx.x) * 4;
    int b = i4 >> 18;
    int u = (i4 >> 8) & 1023;
    int s = i4 & 255;
    int base = (b * NS + s) * 32 + (u >> 5);
    uint32_t bitm = 1u << (u & 31);
    float4 o;
    o.x = (allocW[base] & bitm) ? 1.f : 0.f;
    o.y = (allocW[base + 32] & bitm) ? 1.f : 0.f;
    o.z = (allocW[base + 64] & bitm) ? 1.f : 0.f;
    o.w = (allocW[base + 96] & bitm) ? 1.f : 0.f;
    *(float4*)(out + 4 + i4) = o;
  } else {
    int b = blk - 1024;
    int s = threadIdx.x;
    float4 c = *(const float4*)(capF + (b * NS + s) * 4);
    *(float4*)(out + 4 + NB * NU * NS + (b * NS + s) * 4) = c;
  }
}

extern "C" void kernel_launch(void* const* d_in, const int* in_sizes, int n_in,
                              void* d_out, int out_size, void* d_ws, size_t ws_size,
                              hipStream_t stream) {
  const float* user_enc = (const float*)d_in[0];
  const float* server_enc = (const float*)d_in[1];
  const float* users = (const float*)d_in[2];
  const float* servers = (const float*)d_in[3];
  const uint8_t* connect = (const uint8_t*)d_in[4];
  const float* fd_onehot = (const float*)d_in[5];
  const float* W_state = (const float*)d_in[6];
  const float* b_state = (const float*)d_in[7];
  const float* W_q = (const float*)d_in[8];
  const float* W_k = (const float*)d_in[9];
  const float* W_us = (const float*)d_in[10];
  const float* fd_alpha = (const float*)d_in[11];
  const float* fd_beta = (const float*)d_in[12];
  const float* score_bias = (const float*)d_in[13];

  char* ws = (char*)d_ws;
  size_t off = 0;
  auto take = [&](size_t bytes) -> void* {
    size_t cur = off;
    off = (off + bytes + 255) & ~(size_t)255;
    return (void*)(ws + cur);
  };
  const size_t ctrlBytes = (size_t)(1024 + NB * NGRP * 32) * 4;   // 36 KB
  unsigned* ctrl = (unsigned*)take(ctrlBytes);
  unsigned* det = ctrl + 256;
  float* q = (float*)take((size_t)NB * NU * ND * 4);
  float* kb = (float*)take((size_t)NB * NS * ND * 4);
  float* L0T = (float*)take((size_t)NB * NS * NU * 4);
  float* qc = (float*)take((size_t)NB * NU * 4 * 4);
  float* WS_K = (float*)take((size_t)ND * 4 * 4);
  uint32_t* connT = (uint32_t*)take((size_t)NB * NS * 32 * 4);
  unsigned long long* propA = (unsigned long long*)take((size_t)2 * NB * NS * 8);
  unsigned long long* propB = (unsigned long long*)take((size_t)2 * NB * NS * 8);
  uint32_t* allocW = (uint32_t*)take((size_t)NB * NS * 32 * 4);
  float* capF = (float*)take((size_t)NB * NS * 4 * 4);
  float* outp = (float*)d_out;

  hipMemsetAsync(ctrl, 0, ctrlBytes, stream);
  k_detect<<<64, 256, 0, stream>>>(connect, det);
  k_transpose<<<128, 256, 0, stream>>>(connect, det, connT);
  k_weights<<<1, 256, 0, stream>>>(W_state, W_k, WS_K);
  k_gemm<<<dim3(ND / 64, (NB * NU) / 64, 1), 256, 0, stream>>>(
      user_enc, W_q, q, ND, ND, ND, ND, 0, 0, 0, nullptr, 1.f);
  k_gemm<<<dim3(ND / 64, (NB * NS) / 64, 1), 256, 0, stream>>>(
      server_enc, W_k, kb, ND, ND, ND, ND, 0, 0, 0, b_state, 1.f);
  k_qc<<<NB * NU / 4, 256, 0, stream>>>(q, WS_K, qc);
  k_gemm<<<dim3(NU / 64, NS / 64, NB), 256, 0, stream>>>(
      kb, q, L0T, ND, ND, ND, NU,
      (long)NS * ND, (long)NU * ND, (long)NS * NU, nullptr, 0.0625f);

  // 256 blocks <= 256 CUs: co-residency guaranteed unconditionally
  k_steps4<<<dim3(NB * NGRP), dim3(256), 0, stream>>>(
      L0T, qc, users, servers, connT, fd_onehot, W_us, fd_alpha, fd_beta, score_bias,
      propA, propB, ctrl, allocW, capF, outp);

  k_store<<<1028, 256, 0, stream>>>(allocW, capF, (float*)d_out);
}